// Round 6
// baseline (233.943 us; speedup 1.0000x reference)
//
#include <hip/hip_runtime.h>
#include <hip/hip_bf16.h>
#include <hip/hip_cooperative_groups.h>

namespace cg = cooperative_groups;

#define H   768
#define H4  192
#define EVN 2048
#define KE  6
#define KP  8
#define EE  16384
#define NR  32

typedef __bf16 v8bf __attribute__((ext_vector_type(8)));
typedef float  v4f  __attribute__((ext_vector_type(4)));

__device__ __forceinline__ void gload16(const void* g, void* lds) {
    __builtin_amdgcn_global_load_lds(
        (const __attribute__((address_space(1))) void*)g,
        (__attribute__((address_space(3))) void*)lds, 16, 0, 0);
}
__device__ __forceinline__ float blo(unsigned u) {
    return __uint_as_float(u << 16);
}
__device__ __forceinline__ float bhi(unsigned u) {
    return __uint_as_float(u & 0xffff0000u);
}

// ---------------------------------------------------------------------------
// One fused kernel, 512 blocks x 128 threads, 2 blocks/CU co-resident.
//   Phase A: ev means -> bf16 (4 rows/block); W1^T -> bf16 (blocks 0..287);
//            root phrase means reduced straight to dotr[32][2] (blocks 288..295)
//   Phase B: evw(bf16) = ev @ [W1a|W1b] (+b1 fold), BM=128 BN=48 BK=64,
//            triple-buffer LDS, counted vmcnt, 2 waves x (64x48) tiles
//   Phase C: c = sum(dotr)+bb (per block), then 32 pairs/block logits
// p_lo/p_hi select phases; do_sync enables grid.sync (cooperative launch).
__global__ __launch_bounds__(128) void fused_kernel(
    const float* __restrict__ seq,
    const int* __restrict__ eidx, const float* __restrict__ emask,
    const int* __restrict__ pidx, const float* __restrict__ pmask,
    const int* __restrict__ pair_idx, const int* __restrict__ root_idx,
    const float* __restrict__ W1, const float* __restrict__ b1v,
    const float* __restrict__ Wb, const float* __restrict__ bbv,
    __hip_bfloat16* __restrict__ evb_, __hip_bfloat16* __restrict__ Wt_,
    __hip_bfloat16* __restrict__ evw_, float* __restrict__ dotr,
    float* __restrict__ out, int p_lo, int p_hi, int do_sync) {
    __shared__ short As[3][8192];          // 128 x 64 bf16 per buf (48 KB)
    __shared__ short Bs[3][3072];          //  48 x 64 bf16 per buf (18 KB)

    const int b = blockIdx.x;
    const int t = threadIdx.x;             // 0..127
    const int w = t >> 6;                  // wave 0..1
    const int l = t & 63;
    const float4* seq4 = (const float4*)seq;

    // ======================= Phase A =======================
    if (p_lo <= 0 && p_hi > 0) {
        // ---- 4 event means per block (2 per wave)
#pragma unroll
        for (int rr = 0; rr < 2; ++rr) {
            const int n = b * 4 + w * 2 + rr;
            int idx[KE]; float mk[KE]; float ms = 0.f;
#pragma unroll
            for (int k = 0; k < KE; ++k) {
                idx[k] = eidx[n * KE + k];
                mk[k]  = emask[n * KE + k];
                ms    += mk[k];
            }
            const float inv = 1.f / fmaxf(ms, 1.f);
#pragma unroll
            for (int g = 0; g < 3; ++g) {
                const int t4 = l + g * 64;
                float4 a = {0.f, 0.f, 0.f, 0.f};
#pragma unroll
                for (int k = 0; k < KE; ++k) {
                    float4 v = seq4[idx[k] * H4 + t4];
                    a.x = fmaf(mk[k], v.x, a.x);
                    a.y = fmaf(mk[k], v.y, a.y);
                    a.z = fmaf(mk[k], v.z, a.z);
                    a.w = fmaf(mk[k], v.w, a.w);
                }
                __hip_bfloat16 o[4];
                o[0] = __float2bfloat16(a.x * inv);
                o[1] = __float2bfloat16(a.y * inv);
                o[2] = __float2bfloat16(a.z * inv);
                o[3] = __float2bfloat16(a.w * inv);
                *(uint2*)&evb_[n * H + t4 * 4] = *(uint2*)o;
            }
        }
        if (b < 288) {                     // ---- W1^T tile -> bf16
            float* tile = (float*)&As[0][0];   // [64][65]
            const int k0 = (b % 12) * 64;
            const int j0 = (b / 12) * 64;
            const int s  = (j0 >= H) ? H : 0;
            const int n0 = j0 - s;
            const int c  = t & 63;
            const int r2 = t >> 6;
#pragma unroll
            for (int i = 0; i < 32; ++i) {
                const int r = r2 + i * 2;
                tile[r * 65 + c] = W1[(size_t)(s + k0 + r) * H + n0 + c];
            }
            __syncthreads();
#pragma unroll
            for (int i = 0; i < 32; ++i) {
                const int r = r2 + i * 2;
                Wt_[(size_t)(j0 + r) * H + k0 + c] =
                    __float2bfloat16(tile[c * 65 + r]);
            }
        } else if (b < 296) {              // ---- root means -> dotr[r][2]
#pragma unroll
            for (int rr = 0; rr < 2; ++rr) {
                const int r = (b - 288) * 4 + w * 2 + rr;
                const int pr = root_idx[r];
                int idx[KP]; float mk[KP]; float ms = 0.f;
#pragma unroll
                for (int k = 0; k < KP; ++k) {
                    idx[k] = pidx[pr * KP + k];
                    mk[k]  = pmask[pr * KP + k];
                    ms    += mk[k];
                }
                const float inv = 1.f / fmaxf(ms, 1.f);
                float p0 = 0.f, p1 = 0.f;
#pragma unroll
                for (int g = 0; g < 3; ++g) {
                    const int t4 = l + g * 64;
                    float4 a = {0.f, 0.f, 0.f, 0.f};
#pragma unroll
                    for (int k = 0; k < KP; ++k) {
                        float4 v = seq4[idx[k] * H4 + t4];
                        a.x = fmaf(mk[k], v.x, a.x);
                        a.y = fmaf(mk[k], v.y, a.y);
                        a.z = fmaf(mk[k], v.z, a.z);
                        a.w = fmaf(mk[k], v.w, a.w);
                    }
                    const int d = t4 * 4;
                    float4 q0 = *(const float4*)&Wb[(H + d) * 2];
                    float4 q1 = *(const float4*)&Wb[(H + d) * 2 + 4];
                    p0 += inv * (a.x * q0.x + a.y * q0.z + a.z * q1.x + a.w * q1.z);
                    p1 += inv * (a.x * q0.y + a.y * q0.w + a.z * q1.y + a.w * q1.w);
                }
#pragma unroll
                for (int off = 32; off > 0; off >>= 1) {
                    p0 += __shfl_xor(p0, off, 64);
                    p1 += __shfl_xor(p1, off, 64);
                }
                if (l == 0) {
                    dotr[r * 2 + 0] = p0 * (1.0f / NR);
                    dotr[r * 2 + 1] = p1 * (1.0f / NR);
                }
            }
        }
    }

    if (do_sync) { __threadfence(); cg::this_grid().sync(); }

    // ======================= Phase B =======================
    if (p_lo <= 1 && p_hi > 1) {
        const short* evb = (const short*)evb_;
        const short* Wt  = (const short*)Wt_;

        const int swz = (b & 7) * 64 + (b >> 3);   // 512 blocks, bijective
        const int mt = swz >> 5, nt = swz & 31;    // 16 x 32 tiles
        const int m0 = mt * 128, n0 = nt * 48;
        const int wr = w * 64;

        const short* aSrc[8]; int aOff[8];
#pragma unroll
        for (int c = 0; c < 8; ++c) {
            const int s = c * 128 + t;
            const int r = s >> 3, pg = s & 7, g = pg ^ (r & 7);
            aSrc[c] = evb + (size_t)(m0 + r) * H + g * 8;
            aOff[c] = s * 16;
        }
        const short* bSrc[3]; int bOff[3];
#pragma unroll
        for (int c = 0; c < 3; ++c) {
            const int s = c * 128 + t;
            const int r = s >> 3, pg = s & 7, g = pg ^ (r & 7);
            bSrc[c] = Wt + (size_t)(n0 + r) * H + g * 8;
            bOff[c] = s * 16;
        }

#define STAGE(tile, buf) do {                                              \
    _Pragma("unroll") for (int c_ = 0; c_ < 8; ++c_)                       \
        gload16(aSrc[c_] + (tile) * 64, (char*)As[buf] + aOff[c_]);        \
    _Pragma("unroll") for (int c_ = 0; c_ < 3; ++c_)                       \
        gload16(bSrc[c_] + (tile) * 64, (char*)Bs[buf] + bOff[c_]);        \
} while (0)

        const int fr = l & 15, gq = l >> 4, xm = fr & 7;
        int aRowB[4], bRowB[3];
#pragma unroll
        for (int mi = 0; mi < 4; ++mi) aRowB[mi] = (wr + mi * 16 + fr) * 128;
#pragma unroll
        for (int nj = 0; nj < 3; ++nj) bRowB[nj] = (nj * 16 + fr) * 128;

        v4f acc[4][3] = {};

        STAGE(0, 0);
        STAGE(1, 1);

#pragma unroll
        for (int ks = 0; ks < 12; ++ks) {
            if (ks < 11) { asm volatile("s_waitcnt vmcnt(11)" ::: "memory"); }
            else         { asm volatile("s_waitcnt vmcnt(0)"  ::: "memory"); }
            __builtin_amdgcn_sched_barrier(0);
            __builtin_amdgcn_s_barrier();
            __builtin_amdgcn_sched_barrier(0);
            if (ks < 10) STAGE(ks + 2, (ks + 2) % 3);
            const char* Ab = (const char*)As[ks % 3];
            const char* Bb = (const char*)Bs[ks % 3];
#pragma unroll
            for (int hh = 0; hh < 2; ++hh) {
                const int pgo = ((hh * 4 + gq) ^ xm) * 16;
                v8bf a0 = *(const v8bf*)(Ab + aRowB[0] + pgo);
                v8bf a1 = *(const v8bf*)(Ab + aRowB[1] + pgo);
                v8bf a2 = *(const v8bf*)(Ab + aRowB[2] + pgo);
                v8bf a3 = *(const v8bf*)(Ab + aRowB[3] + pgo);
                v8bf b0 = *(const v8bf*)(Bb + bRowB[0] + pgo);
                v8bf b1 = *(const v8bf*)(Bb + bRowB[1] + pgo);
                v8bf b2 = *(const v8bf*)(Bb + bRowB[2] + pgo);
                acc[0][0] = __builtin_amdgcn_mfma_f32_16x16x32_bf16(a0, b0, acc[0][0], 0, 0, 0);
                acc[0][1] = __builtin_amdgcn_mfma_f32_16x16x32_bf16(a0, b1, acc[0][1], 0, 0, 0);
                acc[0][2] = __builtin_amdgcn_mfma_f32_16x16x32_bf16(a0, b2, acc[0][2], 0, 0, 0);
                acc[1][0] = __builtin_amdgcn_mfma_f32_16x16x32_bf16(a1, b0, acc[1][0], 0, 0, 0);
                acc[1][1] = __builtin_amdgcn_mfma_f32_16x16x32_bf16(a1, b1, acc[1][1], 0, 0, 0);
                acc[1][2] = __builtin_amdgcn_mfma_f32_16x16x32_bf16(a1, b2, acc[1][2], 0, 0, 0);
                acc[2][0] = __builtin_amdgcn_mfma_f32_16x16x32_bf16(a2, b0, acc[2][0], 0, 0, 0);
                acc[2][1] = __builtin_amdgcn_mfma_f32_16x16x32_bf16(a2, b1, acc[2][1], 0, 0, 0);
                acc[2][2] = __builtin_amdgcn_mfma_f32_16x16x32_bf16(a2, b2, acc[2][2], 0, 0, 0);
                acc[3][0] = __builtin_amdgcn_mfma_f32_16x16x32_bf16(a3, b0, acc[3][0], 0, 0, 0);
                acc[3][1] = __builtin_amdgcn_mfma_f32_16x16x32_bf16(a3, b1, acc[3][1], 0, 0, 0);
                acc[3][2] = __builtin_amdgcn_mfma_f32_16x16x32_bf16(a3, b2, acc[3][2], 0, 0, 0);
            }
        }
#undef STAGE

        float bv[3];
#pragma unroll
        for (int nj = 0; nj < 3; ++nj) {
            const int ocol = n0 + nj * 16 + fr;
            bv[nj] = (ocol >= H) ? b1v[ocol - H] : 0.f;
        }
#pragma unroll
        for (int mi = 0; mi < 4; ++mi)
#pragma unroll
            for (int nj = 0; nj < 3; ++nj) {
                const int ocol = n0 + nj * 16 + fr;
#pragma unroll
                for (int r = 0; r < 4; ++r) {
                    const int orow = m0 + wr + mi * 16 + gq * 4 + r;
                    evw_[(size_t)orow * 1536 + ocol] =
                        __float2bfloat16(acc[mi][nj][r] + bv[nj]);
                }
            }
    }

    if (do_sync) { __threadfence(); cg::this_grid().sync(); }

    // ======================= Phase C =======================
    if (p_lo <= 2 && p_hi > 2) {
        // c = sum_r dotr[r] + bb  (wave 0 reduces, LDS broadcast)
        float* cc = (float*)&Bs[0][0];
        {
            float s0 = 0.f, s1 = 0.f;
            if (t < 32) { s0 = dotr[t * 2]; s1 = dotr[t * 2 + 1]; }
#pragma unroll
            for (int off = 32; off > 0; off >>= 1) {
                s0 += __shfl_xor(s0, off, 64);
                s1 += __shfl_xor(s1, off, 64);
            }
            if (t == 0) { cc[0] = s0 + bbv[0]; cc[1] = s1 + bbv[1]; }
            __syncthreads();
        }
        const float c0 = cc[0], c1 = cc[1];

        const ushort* evw = (const ushort*)evw_;
        const int base = b * 32 + w * 16;
        const int jb0 = l * 6, jb1 = 384 + l * 6;
        // hoist Wb fragments (same j's for every pair)
        const float4 wa0 = *(const float4*)&Wb[jb0 * 2];
        const float4 wa1 = *(const float4*)&Wb[jb0 * 2 + 4];
        const float4 wa2 = *(const float4*)&Wb[jb0 * 2 + 8];
        const float4 wb0 = *(const float4*)&Wb[jb1 * 2];
        const float4 wb1 = *(const float4*)&Wb[jb1 * 2 + 4];
        const float4 wb2 = *(const float4*)&Wb[jb1 * 2 + 8];

        uint3 cA0, cA1, cB0, cB1;          // current pair data
        {
            const int i = base;
            const int p0 = pair_idx[i * 2], p1 = pair_idx[i * 2 + 1];
            const ushort* ra = evw + (size_t)p0 * 1536;
            const ushort* rb = evw + (size_t)p1 * 1536 + H;
            cA0 = *(const uint3*)(ra + jb0); cA1 = *(const uint3*)(ra + jb1);
            cB0 = *(const uint3*)(rb + jb0); cB1 = *(const uint3*)(rb + jb1);
        }
#pragma unroll
        for (int pp = 0; pp < 16; ++pp) {
            uint3 nA0, nA1, nB0, nB1;
            if (pp < 15) {                 // prefetch next pair
                const int i = base + pp + 1;
                const int p0 = pair_idx[i * 2], p1 = pair_idx[i * 2 + 1];
                const ushort* ra = evw + (size_t)p0 * 1536;
                const ushort* rb = evw + (size_t)p1 * 1536 + H;
                nA0 = *(const uint3*)(ra + jb0); nA1 = *(const uint3*)(ra + jb1);
                nB0 = *(const uint3*)(rb + jb0); nB1 = *(const uint3*)(rb + jb1);
            }
            float n0 = fmaxf(blo(cA0.x) + blo(cB0.x), 0.f);
            float n1 = fmaxf(bhi(cA0.x) + bhi(cB0.x), 0.f);
            float n2 = fmaxf(blo(cA0.y) + blo(cB0.y), 0.f);
            float n3 = fmaxf(bhi(cA0.y) + bhi(cB0.y), 0.f);
            float n4 = fmaxf(blo(cA0.z) + blo(cB0.z), 0.f);
            float n5 = fmaxf(bhi(cA0.z) + bhi(cB0.z), 0.f);
            float acc0 = n0 * wa0.x + n1 * wa0.z + n2 * wa1.x + n3 * wa1.z + n4 * wa2.x + n5 * wa2.z;
            float acc1 = n0 * wa0.y + n1 * wa0.w + n2 * wa1.y + n3 * wa1.w + n4 * wa2.y + n5 * wa2.w;
            n0 = fmaxf(blo(cA1.x) + blo(cB1.x), 0.f);
            n1 = fmaxf(bhi(cA1.x) + bhi(cB1.x), 0.f);
            n2 = fmaxf(blo(cA1.y) + blo(cB1.y), 0.f);
            n3 = fmaxf(bhi(cA1.y) + bhi(cB1.y), 0.f);
            n4 = fmaxf(blo(cA1.z) + blo(cB1.z), 0.f);
            n5 = fmaxf(bhi(cA1.z) + bhi(cB1.z), 0.f);
            acc0 += n0 * wb0.x + n1 * wb0.z + n2 * wb1.x + n3 * wb1.z + n4 * wb2.x + n5 * wb2.z;
            acc1 += n0 * wb0.y + n1 * wb0.w + n2 * wb1.y + n3 * wb1.w + n4 * wb2.y + n5 * wb2.w;
#pragma unroll
            for (int off = 32; off > 0; off >>= 1) {
                acc0 += __shfl_xor(acc0, off, 64);
                acc1 += __shfl_xor(acc1, off, 64);
            }
            if (l == 0) {
                const int i = base + pp;
                out[i * 2 + 0] = acc0 + c0;
                out[i * 2 + 1] = acc1 + c1;
            }
            cA0 = nA0; cA1 = nA1; cB0 = nB0; cB1 = nB1;
        }
    }
}

// ---------------------------------------------------------------------------
extern "C" void kernel_launch(void* const* d_in, const int* in_sizes, int n_in,
                              void* d_out, int out_size, void* d_ws, size_t ws_size,
                              hipStream_t stream) {
    const float* seq         = (const float*)d_in[0];
    const int*   phrase_idx  = (const int*)  d_in[1];
    const float* phrase_mask = (const float*)d_in[2];
    const int*   event_idx   = (const int*)  d_in[3];
    const float* event_mask  = (const float*)d_in[4];
    const int*   pair_idx    = (const int*)  d_in[5];
    const int*   root_idx    = (const int*)  d_in[6];
    const float* W1          = (const float*)d_in[7];
    const float* b1          = (const float*)d_in[8];
    const float* Wb          = (const float*)d_in[9];
    const float* bb          = (const float*)d_in[10];
    float* out = (float*)d_out;

    // ws layout (bytes)
    char* wsb = (char*)d_ws;
    __hip_bfloat16* evb = (__hip_bfloat16*)wsb;                 // 3,145,728
    __hip_bfloat16* Wt  = (__hip_bfloat16*)(wsb + 3145728);     // 2,359,296
    __hip_bfloat16* evw = (__hip_bfloat16*)(wsb + 5505024);     // 6,291,456
    float* dotr = (float*)(wsb + 11796480);                     //       256

    int lo = 0, hi = 3, sync1 = 1;
    void* args[] = {
        (void*)&seq, (void*)&event_idx, (void*)&event_mask,
        (void*)&phrase_idx, (void*)&phrase_mask,
        (void*)&pair_idx, (void*)&root_idx,
        (void*)&W1, (void*)&b1, (void*)&Wb, (void*)&bb,
        (void*)&evb, (void*)&Wt, (void*)&evw, (void*)&dotr, (void*)&out,
        (void*)&lo, (void*)&hi, (void*)&sync1
    };
    hipError_t err = hipLaunchCooperativeKernel(
        (const void*)fused_kernel, dim3(512), dim3(128), args, 0, stream);
    if (err != hipSuccess) {
        // fallback: phase-sliced normal launches (grid.sync compiled out)
        fused_kernel<<<512, 128, 0, stream>>>(
            seq, event_idx, event_mask, phrase_idx, phrase_mask, pair_idx,
            root_idx, W1, b1, Wb, bb, evb, Wt, evw, dotr, out, 0, 1, 0);
        fused_kernel<<<512, 128, 0, stream>>>(
            seq, event_idx, event_mask, phrase_idx, phrase_mask, pair_idx,
            root_idx, W1, b1, Wb, bb, evb, Wt, evw, dotr, out, 1, 2, 0);
        fused_kernel<<<512, 128, 0, stream>>>(
            seq, event_idx, event_mask, phrase_idx, phrase_mask, pair_idx,
            root_idx, W1, b1, Wb, bb, evb, Wt, evw, dotr, out, 2, 3, 0);
    }
}

// Round 7
// 31.850 us; speedup vs baseline: 7.3453x; 7.3453x over previous
//
#include <hip/hip_runtime.h>
#include <hip/hip_bf16.h>

#define H   768
#define H4  192
#define EVN 2048
#define KE  6
#define KP  8
#define EE  16384
#define NR  32

typedef __bf16 v8bf __attribute__((ext_vector_type(8)));
typedef float  v4f  __attribute__((ext_vector_type(4)));

__device__ __forceinline__ void gload16(const void* g, void* lds) {
    __builtin_amdgcn_global_load_lds(
        (const __attribute__((address_space(1))) void*)g,
        (__attribute__((address_space(3))) void*)lds, 16, 0, 0);
}
__device__ __forceinline__ float blo(unsigned u) {
    return __uint_as_float(u << 16);
}
__device__ __forceinline__ float bhi(unsigned u) {
    return __uint_as_float(u & 0xffff0000u);
}

// ---------------------------------------------------------------------------
// K_pre: fused  ev_mean (blocks 0..511, 4 rows/block, 1 wave/row)
//               root_mean (blocks 512..519, 4 roots/block)
//               W1 transpose->bf16 (blocks 520..807)
__global__ __launch_bounds__(256) void pre_kernel(
    const float* __restrict__ seq,
    const int* __restrict__ eidx, const float* __restrict__ emask,
    const int* __restrict__ pidx, const float* __restrict__ pmask,
    const int* __restrict__ root_idx, const float* __restrict__ W1,
    __hip_bfloat16* __restrict__ evb, __hip_bfloat16* __restrict__ Wt,
    float* __restrict__ phr) {
    __shared__ float tile[64][65];
    const int b = blockIdx.x;
    const int t = threadIdx.x;
    const float4* seq4 = (const float4*)seq;

    if (b < 512) {                         // ---- event means -> bf16
        const int w = t >> 6, l = t & 63;
        const int n = b * 4 + w;
        int idx[KE]; float mk[KE]; float ms = 0.f;
#pragma unroll
        for (int k = 0; k < KE; ++k) {
            idx[k] = eidx[n * KE + k];
            mk[k]  = emask[n * KE + k];
            ms    += mk[k];
        }
        const float inv = 1.f / fmaxf(ms, 1.f);
#pragma unroll
        for (int g = 0; g < 3; ++g) {
            const int t4 = l + g * 64;
            float4 acc = {0.f, 0.f, 0.f, 0.f};
#pragma unroll
            for (int k = 0; k < KE; ++k) {
                float4 v = seq4[idx[k] * H4 + t4];
                acc.x = fmaf(mk[k], v.x, acc.x);
                acc.y = fmaf(mk[k], v.y, acc.y);
                acc.z = fmaf(mk[k], v.z, acc.z);
                acc.w = fmaf(mk[k], v.w, acc.w);
            }
            __hip_bfloat16 o[4];
            o[0] = __float2bfloat16(acc.x * inv);
            o[1] = __float2bfloat16(acc.y * inv);
            o[2] = __float2bfloat16(acc.z * inv);
            o[3] = __float2bfloat16(acc.w * inv);
            *(uint2*)&evb[n * H + t4 * 4] = *(uint2*)o;
        }
    } else if (b < 520) {                  // ---- root phrase means (f32)
        const int w = t >> 6, l = t & 63;
        const int r = (b - 512) * 4 + w;
        const int pr = root_idx[r];
        int idx[KP]; float mk[KP]; float ms = 0.f;
#pragma unroll
        for (int k = 0; k < KP; ++k) {
            idx[k] = pidx[pr * KP + k];
            mk[k]  = pmask[pr * KP + k];
            ms    += mk[k];
        }
        const float inv = 1.f / fmaxf(ms, 1.f);
#pragma unroll
        for (int g = 0; g < 3; ++g) {
            const int t4 = l + g * 64;
            float4 acc = {0.f, 0.f, 0.f, 0.f};
#pragma unroll
            for (int k = 0; k < KP; ++k) {
                float4 v = seq4[idx[k] * H4 + t4];
                acc.x = fmaf(mk[k], v.x, acc.x);
                acc.y = fmaf(mk[k], v.y, acc.y);
                acc.z = fmaf(mk[k], v.z, acc.z);
                acc.w = fmaf(mk[k], v.w, acc.w);
            }
            float4 o = {acc.x * inv, acc.y * inv, acc.z * inv, acc.w * inv};
            ((float4*)phr)[r * H4 + t4] = o;
        }
    } else {                               // ---- W1^T -> bf16
        const int b2 = b - 520;
        const int k0 = (b2 % 12) * 64;
        const int j0 = (b2 / 12) * 64;
        const int s  = (j0 >= H) ? H : 0;
        const int n0 = j0 - s;
        const int c  = t & 63;
        const int r0 = t >> 6;
#pragma unroll
        for (int i = 0; i < 16; ++i) {
            const int r = r0 + i * 4;
            tile[r][c] = W1[(size_t)(s + k0 + r) * H + n0 + c];
        }
        __syncthreads();
#pragma unroll
        for (int i = 0; i < 16; ++i) {
            const int r = r0 + i * 4;
            Wt[(size_t)(j0 + r) * H + k0 + c] = __float2bfloat16(tile[c][r]);
        }
    }
}

// ---------------------------------------------------------------------------
// K_gemm blocks 0..383: evW(bf16) = ev @ [W1a | W1b] (+ b1 on cols >= 768)
//   BM=128, BN=64, BK=64; 256 threads = 4 waves (2x2), wave tile 64x32
//   (4x2 frags). A,B LDS triple-buffered via global_load_lds w=16 with the
//   8-granule XOR involution (pre-swizzled source + same-involution read).
//   2-deep prefetch, COUNTED vmcnt(6) mid-loop (6 gloads/thread/stage).
// block 384: vroot/c computation.
__global__ __launch_bounds__(256) void gemm_kernel(
    const __hip_bfloat16* __restrict__ evb_,
    const __hip_bfloat16* __restrict__ Wt_,
    const float* __restrict__ b1v,
    const float* __restrict__ phr, const float* __restrict__ Wb,
    const float* __restrict__ bbv,
    __hip_bfloat16* __restrict__ evw, float* __restrict__ cvec) {
    __shared__ short As[3][8192];          // 128 x 64 bf16 per buf = 16 KB
    __shared__ short Bs[3][4096];          //  64 x 64 bf16 per buf =  8 KB

    if (blockIdx.x == 384) {               // ---- vroot + c (256 threads)
        float* r0s = (float*)&As[0][0];
        float* r1s = r0s + 256;
        const int t = threadIdx.x;
        float p0 = 0.f, p1 = 0.f;
#pragma unroll
        for (int w = 0; w < 3; ++w) {
            const int d = t + w * 256;
            float s = 0.f;
            for (int r = 0; r < NR; ++r) s += phr[r * H + d];
            const float v = s * (1.0f / NR);
            p0 = fmaf(v, Wb[(H + d) * 2 + 0], p0);
            p1 = fmaf(v, Wb[(H + d) * 2 + 1], p1);
        }
        r0s[t] = p0; r1s[t] = p1;
        __syncthreads();
        for (int off = 128; off > 0; off >>= 1) {
            if (t < off) { r0s[t] += r0s[t + off]; r1s[t] += r1s[t + off]; }
            __syncthreads();
        }
        if (t == 0) { cvec[0] = r0s[0] + bbv[0]; cvec[1] = r1s[0] + bbv[1]; }
        return;
    }

    const short* evb = (const short*)evb_;
    const short* Wt  = (const short*)Wt_;

    const int bid = blockIdx.x;            // 384 blocks, %8==0
    const int swz = (bid & 7) * 48 + (bid >> 3);
    const int mt = swz / 24, nt = swz % 24;
    const int m0 = mt * 128, n0 = nt * 64;

    const int t = threadIdx.x;             // 0..255
    const int l = t & 63;
    const int w = t >> 6;                  // wave 0..3
    const int wr = (w >> 1) * 64;          // wave row base
    const int wc = (w & 1) * 32;           // wave col base

    // A staging: 1024 slots; slot s -> row s>>3, phys granule s&7 holds
    // logical (s&7)^(row&7). LDS dest = uniform base + lane*16 (HW rule).
    const short* aSrc[4]; int aOff[4];
#pragma unroll
    for (int c = 0; c < 4; ++c) {
        const int s = c * 256 + t;
        const int r = s >> 3, pg = s & 7, g = pg ^ (r & 7);
        aSrc[c] = evb + (size_t)(m0 + r) * H + g * 8;
        aOff[c] = s * 16;                  // bytes
    }
    // B staging: 512 slots
    const short* bSrc[2]; int bOff[2];
#pragma unroll
    for (int c = 0; c < 2; ++c) {
        const int s = c * 256 + t;
        const int r = s >> 3, pg = s & 7, g = pg ^ (r & 7);
        bSrc[c] = Wt + (size_t)(n0 + r) * H + g * 8;
        bOff[c] = s * 16;
    }

#define STAGE(tile, buf) do {                                              \
    _Pragma("unroll") for (int c_ = 0; c_ < 4; ++c_)                       \
        gload16(aSrc[c_] + (tile) * 64, (char*)As[buf] + aOff[c_]);        \
    _Pragma("unroll") for (int c_ = 0; c_ < 2; ++c_)                       \
        gload16(bSrc[c_] + (tile) * 64, (char*)Bs[buf] + bOff[c_]);        \
} while (0)

    // fragment read geometry
    const int fr = l & 15, gq = l >> 4, xm = fr & 7;
    int aRowB[4], bRowB[2];                // LDS byte base per frag row
#pragma unroll
    for (int mi = 0; mi < 4; ++mi) aRowB[mi] = (wr + mi * 16 + fr) * 128;
#pragma unroll
    for (int nj = 0; nj < 2; ++nj) bRowB[nj] = (wc + nj * 16 + fr) * 128;

    v4f acc[4][2] = {};

    STAGE(0, 0);
    STAGE(1, 1);

#pragma unroll
    for (int ks = 0; ks < 12; ++ks) {
        if (ks < 11) { asm volatile("s_waitcnt vmcnt(6)" ::: "memory"); }
        else         { asm volatile("s_waitcnt vmcnt(0)" ::: "memory"); }
        __builtin_amdgcn_sched_barrier(0);
        __builtin_amdgcn_s_barrier();
        __builtin_amdgcn_sched_barrier(0);
        if (ks < 10) STAGE(ks + 2, (ks + 2) % 3);
        const char* Ab = (const char*)As[ks % 3];
        const char* Bb = (const char*)Bs[ks % 3];
#pragma unroll
        for (int hh = 0; hh < 2; ++hh) {
            const int pgo = ((hh * 4 + gq) ^ xm) * 16;   // byte offset
            v8bf a0 = *(const v8bf*)(Ab + aRowB[0] + pgo);
            v8bf a1 = *(const v8bf*)(Ab + aRowB[1] + pgo);
            v8bf a2 = *(const v8bf*)(Ab + aRowB[2] + pgo);
            v8bf a3 = *(const v8bf*)(Ab + aRowB[3] + pgo);
            v8bf b0 = *(const v8bf*)(Bb + bRowB[0] + pgo);
            v8bf b1 = *(const v8bf*)(Bb + bRowB[1] + pgo);
            acc[0][0] = __builtin_amdgcn_mfma_f32_16x16x32_bf16(a0, b0, acc[0][0], 0, 0, 0);
            acc[0][1] = __builtin_amdgcn_mfma_f32_16x16x32_bf16(a0, b1, acc[0][1], 0, 0, 0);
            acc[1][0] = __builtin_amdgcn_mfma_f32_16x16x32_bf16(a1, b0, acc[1][0], 0, 0, 0);
            acc[1][1] = __builtin_amdgcn_mfma_f32_16x16x32_bf16(a1, b1, acc[1][1], 0, 0, 0);
            acc[2][0] = __builtin_amdgcn_mfma_f32_16x16x32_bf16(a2, b0, acc[2][0], 0, 0, 0);
            acc[2][1] = __builtin_amdgcn_mfma_f32_16x16x32_bf16(a2, b1, acc[2][1], 0, 0, 0);
            acc[3][0] = __builtin_amdgcn_mfma_f32_16x16x32_bf16(a3, b0, acc[3][0], 0, 0, 0);
            acc[3][1] = __builtin_amdgcn_mfma_f32_16x16x32_bf16(a3, b1, acc[3][1], 0, 0, 0);
        }
    }
#undef STAGE

    // epilogue: bf16 store, b1 folded into the second W half (cols >= 768)
    float bv[2];
#pragma unroll
    for (int nj = 0; nj < 2; ++nj) {
        const int ocol = n0 + wc + nj * 16 + fr;
        bv[nj] = (ocol >= H) ? b1v[ocol - H] : 0.f;
    }
#pragma unroll
    for (int mi = 0; mi < 4; ++mi)
#pragma unroll
        for (int nj = 0; nj < 2; ++nj) {
            const int ocol = n0 + wc + nj * 16 + fr;
#pragma unroll
            for (int r = 0; r < 4; ++r) {
                const int orow = m0 + wr + mi * 16 + gq * 4 + r;
                evw[(size_t)orow * 1536 + ocol] =
                    __float2bfloat16(acc[mi][nj][r] + bv[nj]);
            }
        }
}

// ---------------------------------------------------------------------------
// K4: out[i,l] = sum_j relu(evw[p0,j] + evw[p1,768+j]) * Wb[j,l] + c[l]
// one wave per pair; lane covers 6 j's per half (uint3 = 6 bf16)
__global__ __launch_bounds__(256) void pair_logits_kernel(
    const __hip_bfloat16* __restrict__ evw_, const int* __restrict__ pair_idx,
    const float* __restrict__ Wb, const float* __restrict__ cvec,
    float* __restrict__ out) {
    const ushort* evw = (const ushort*)evw_;
    const int wave = threadIdx.x >> 6;
    const int lane = threadIdx.x & 63;
    const int i = blockIdx.x * 4 + wave;
    const int p0 = pair_idx[i * 2 + 0];
    const int p1 = pair_idx[i * 2 + 1];
    const ushort* ra = evw + (size_t)p0 * 1536;
    const ushort* rb = evw + (size_t)p1 * 1536 + H;
    float acc0 = 0.f, acc1 = 0.f;
#pragma unroll
    for (int h = 0; h < 2; ++h) {
        const int j = h * 384 + lane * 6;
        uint3 ua = *(const uint3*)(ra + j);
        uint3 ub = *(const uint3*)(rb + j);
        float4 w0 = *(const float4*)(Wb + j * 2);
        float4 w1 = *(const float4*)(Wb + j * 2 + 4);
        float4 w2 = *(const float4*)(Wb + j * 2 + 8);
        float n0 = fmaxf(blo(ua.x) + blo(ub.x), 0.f);
        float n1 = fmaxf(bhi(ua.x) + bhi(ub.x), 0.f);
        float n2 = fmaxf(blo(ua.y) + blo(ub.y), 0.f);
        float n3 = fmaxf(bhi(ua.y) + bhi(ub.y), 0.f);
        float n4 = fmaxf(blo(ua.z) + blo(ub.z), 0.f);
        float n5 = fmaxf(bhi(ua.z) + bhi(ub.z), 0.f);
        acc0 += n0 * w0.x + n1 * w0.z + n2 * w1.x + n3 * w1.z + n4 * w2.x + n5 * w2.z;
        acc1 += n0 * w0.y + n1 * w0.w + n2 * w1.y + n3 * w1.w + n4 * w2.y + n5 * w2.w;
    }
#pragma unroll
    for (int off = 32; off > 0; off >>= 1) {
        acc0 += __shfl_xor(acc0, off, 64);
        acc1 += __shfl_xor(acc1, off, 64);
    }
    if (lane == 0) {
        out[i * 2 + 0] = acc0 + cvec[0];
        out[i * 2 + 1] = acc1 + cvec[1];
    }
}

// ---------------------------------------------------------------------------
extern "C" void kernel_launch(void* const* d_in, const int* in_sizes, int n_in,
                              void* d_out, int out_size, void* d_ws, size_t ws_size,
                              hipStream_t stream) {
    const float* seq         = (const float*)d_in[0];
    const int*   phrase_idx  = (const int*)  d_in[1];
    const float* phrase_mask = (const float*)d_in[2];
    const int*   event_idx   = (const int*)  d_in[3];
    const float* event_mask  = (const float*)d_in[4];
    const int*   pair_idx    = (const int*)  d_in[5];
    const int*   root_idx    = (const int*)  d_in[6];
    const float* W1          = (const float*)d_in[7];
    const float* b1          = (const float*)d_in[8];
    const float* Wb          = (const float*)d_in[9];
    const float* bb          = (const float*)d_in[10];
    float* out = (float*)d_out;

    // ws layout (bytes)
    char* wsb = (char*)d_ws;
    __hip_bfloat16* evb = (__hip_bfloat16*)wsb;                 // 3,145,728
    __hip_bfloat16* Wt  = (__hip_bfloat16*)(wsb + 3145728);     // 2,359,296
    __hip_bfloat16* evw = (__hip_bfloat16*)(wsb + 5505024);     // 6,291,456
    float* phr = (float*)(wsb + 11796480);                      //    98,304
    float* c   = (float*)(wsb + 11894784);                      //         8

    pre_kernel<<<808, 256, 0, stream>>>(seq, event_idx, event_mask,
                                        phrase_idx, phrase_mask, root_idx,
                                        W1, evb, Wt, phr);
    gemm_kernel<<<385, 256, 0, stream>>>(evb, Wt, b1, phr, Wb, bb, evw, c);
    pair_logits_kernel<<<EE / 4, 256, 0, stream>>>(evw, pair_idx, Wb, c, out);
}